// Round 4
// baseline (860.662 us; speedup 1.0000x reference)
//
#include <hip/hip_runtime.h>

#define LN_EPS 1e-5f

typedef short s8v __attribute__((ext_vector_type(8)));
typedef float f4v __attribute__((ext_vector_type(4)));

constexpr int BS = 32, LA = 300, LB = 1024, H = 512;
constexpr long RTOT = (long)H * H;  // 262144 W rows (r = k*512 + d)

// ws layout (bytes):
//   [0,       524288)   part  [32][8][512] fp32
//   [524288,  557056)   bmh   [32][512] bf16 (hi plane)
//   [557056,  589824)   bml   [32][512] bf16 (lo plane)
//   [589824,  +16MiB)   thi   [32][512][512] bf16 (hi plane)
//   [+16MiB,  +32MiB)   tlo   [32][512][512] bf16 (lo plane)

union U8 { s8v v; unsigned u[4]; };
union FU { float f; unsigned u; };

__device__ inline unsigned pack_hi16(unsigned a, unsigned b) {
  return (a >> 16) | (b & 0xffff0000u);  // elem0 = a.hi16 (low half), elem1 = b.hi16
}

// Split 8 fp32 into hi/lo bf16 (truncation split; lo compensates hi exactly).
__device__ inline void split8(const f4v w0, const f4v w1, s8v& hi, s8v& lo) {
  FU f[8] = {{w0.x}, {w0.y}, {w0.z}, {w0.w}, {w1.x}, {w1.y}, {w1.z}, {w1.w}};
  U8 h, l;
#pragma unroll
  for (int p = 0; p < 4; ++p) {
    const unsigned ua = f[2 * p].u, ub = f[2 * p + 1].u;
    h.u[p] = pack_hi16(ua, ub);
    FU ra, rb;
    ra.f = f[2 * p].f - __uint_as_float(ua & 0xffff0000u);
    rb.f = f[2 * p + 1].f - __uint_as_float(ub & 0xffff0000u);
    l.u[p] = pack_hi16(ra.u, rb.u);
  }
  hi = h.v;
  lo = l.v;
}

// ---------------- kernel 1a: partial sums of feat_b over len_b ----------------
__global__ __launch_bounds__(512) void k_bmean_part(const float* __restrict__ fb,
                                                    float* __restrict__ part) {
  const int b = blockIdx.x >> 3, c = blockIdx.x & 7;
  const int e = threadIdx.x;
  const float* src = fb + ((long)b * LB + (long)c * 128) * H + e;
  float s = 0.f;
#pragma unroll 8
  for (int j = 0; j < 128; ++j) s += __builtin_nontemporal_load(&src[(long)j * H]);
  part[((b << 3) + c) * H + e] = s;
}

// ---------------- kernel 1b: reduce partials -> bm hi/lo bf16 planes ----------------
__global__ __launch_bounds__(512) void k_bmean_final(const float* __restrict__ part,
                                                     unsigned short* __restrict__ bmh,
                                                     unsigned short* __restrict__ bml) {
  const int b = blockIdx.x, e = threadIdx.x;
  float s = 0.f;
#pragma unroll
  for (int c = 0; c < 8; ++c) s += part[((b << 3) + c) * H + e];
  const float v = s * (1.f / LB);
  FU u; u.f = v;
  bmh[b * H + e] = (unsigned short)(u.u >> 16);
  FU r; r.f = v - __uint_as_float(u.u & 0xffff0000u);
  bml[b * H + e] = (unsigned short)(r.u >> 16);
}

// ---------------- kernel 2: t[b, r] = dot(W[r, :], bm[b, :]) via hi/lo bf16 MFMA ----------------
// (byte-identical to the R2-passing version)
__global__ __launch_bounds__(256) void k_wt(const float* __restrict__ W,
                                            const unsigned short* __restrict__ bmh,
                                            const unsigned short* __restrict__ bml,
                                            unsigned short* __restrict__ thi,
                                            unsigned short* __restrict__ tlo) {
  const int tid = threadIdx.x, wv = tid >> 6, ln = tid & 63;
  const int l16 = ln & 15, kg = ln >> 4;
  const long r0 = (long)blockIdx.x * 256 + wv * 64;

  f4v acc[2][4];
#pragma unroll
  for (int m = 0; m < 2; ++m)
#pragma unroll
    for (int n = 0; n < 4; ++n) acc[m][n] = (f4v){0.f, 0.f, 0.f, 0.f};

  const float* wp = W + (r0 + l16) * (long)H + kg * 8;
  const int aoff = l16 * H + kg * 8;

#define LOADW(W0, W1, E)                                          \
  _Pragma("unroll")                                               \
  for (int nt = 0; nt < 4; ++nt) {                                \
    const f4v* p = (const f4v*)(wp + (long)nt * 16 * H + (E));    \
    W0[nt] = __builtin_nontemporal_load(p);                       \
    W1[nt] = __builtin_nontemporal_load(p + 1);                   \
  }

#define COMPUTEW(W0, W1, E)                                                                \
  {                                                                                        \
    const s8v ah0 = *(const s8v*)(bmh + aoff + (E));                                       \
    const s8v al0 = *(const s8v*)(bml + aoff + (E));                                       \
    const s8v ah1 = *(const s8v*)(bmh + 16 * H + aoff + (E));                              \
    const s8v al1 = *(const s8v*)(bml + 16 * H + aoff + (E));                              \
    _Pragma("unroll")                                                                      \
    for (int nt = 0; nt < 4; ++nt) {                                                       \
      s8v wh, wl;                                                                          \
      split8(W0[nt], W1[nt], wh, wl);                                                      \
      acc[0][nt] = __builtin_amdgcn_mfma_f32_16x16x32_bf16(ah0, wh, acc[0][nt], 0, 0, 0);  \
      acc[0][nt] = __builtin_amdgcn_mfma_f32_16x16x32_bf16(al0, wh, acc[0][nt], 0, 0, 0);  \
      acc[0][nt] = __builtin_amdgcn_mfma_f32_16x16x32_bf16(ah0, wl, acc[0][nt], 0, 0, 0);  \
      acc[1][nt] = __builtin_amdgcn_mfma_f32_16x16x32_bf16(ah1, wh, acc[1][nt], 0, 0, 0);  \
      acc[1][nt] = __builtin_amdgcn_mfma_f32_16x16x32_bf16(al1, wh, acc[1][nt], 0, 0, 0);  \
      acc[1][nt] = __builtin_amdgcn_mfma_f32_16x16x32_bf16(ah1, wl, acc[1][nt], 0, 0, 0);  \
    }                                                                                      \
  }

  f4v wa0[4], wa1[4], wb0[4], wb1[4];
  LOADW(wa0, wa1, 0);
  for (int e0 = 0; e0 < H; e0 += 64) {
    LOADW(wb0, wb1, e0 + 32);
    COMPUTEW(wa0, wa1, e0);
    if (e0 + 64 < H) LOADW(wa0, wa1, e0 + 64);
    COMPUTEW(wb0, wb1, e0 + 32);
  }
#undef LOADW
#undef COMPUTEW

  // D layout: row(m=batch) = kg*4 + j, col(n=W-row) = l16; store t split hi/lo
#pragma unroll
  for (int m = 0; m < 2; ++m)
#pragma unroll
    for (int nt = 0; nt < 4; ++nt)
#pragma unroll
      for (int j = 0; j < 4; ++j) {
        const float v = acc[m][nt][j];
        const long idx = (long)(m * 16 + kg * 4 + j) * RTOT + r0 + nt * 16 + l16;
        FU u; u.f = v;
        thi[idx] = (unsigned short)(u.u >> 16);
        FU r; r.f = v - __uint_as_float(u.u & 0xffff0000u);
        tlo[idx] = (unsigned short)(r.u >> 16);
      }
}

// ---------------- kernel 3: fused GEMM + bias + residual + LayerNorm, one pass ----------------
// Block = 256 thr (4 waves), tile = 32a x 512k. Wave wv owns k-slice [wv*128, wv*128+128).
// Main d-loop math is copied verbatim from the verified k_fused (acc[mt][nt], triple MFMA).
// Epilogue: x = acc + bias[k] + fa[b,a,k]; per-row stats via shfl_xor within 16-lane
// groups (lane = kg*16+l16; xor 1/2/4/8 toggles l16 only) + 2KB LDS across the 4 waves.
__global__ __launch_bounds__(256) void k_fused_ln(const float* __restrict__ fa,
                                                  const unsigned short* __restrict__ thi,
                                                  const unsigned short* __restrict__ tlo,
                                                  const float* __restrict__ bias,
                                                  const float* __restrict__ gamma,
                                                  const float* __restrict__ beta,
                                                  float* __restrict__ out) {
  const int tid = threadIdx.x, wv = tid >> 6, ln = tid & 63;
  const int l16 = ln & 15, kg = ln >> 4;
  const int b = blockIdx.y, a0 = blockIdx.x * 32, k0 = wv * 128;

  __shared__ float sums[4][32], ssq[4][32];

  f4v acc[2][8];
#pragma unroll
  for (int m = 0; m < 2; ++m)
#pragma unroll
    for (int n = 0; n < 8; ++n) acc[m][n] = (f4v){0.f, 0.f, 0.f, 0.f};

  const float* fab = fa + (long)b * LA * H;
  const unsigned short* th = thi + (long)b * RTOT;
  const unsigned short* tl = tlo + (long)b * RTOT;

  for (int d0 = 0; d0 < H; d0 += 32) {
    s8v afh[2], afl[2];
#pragma unroll
    for (int mt = 0; mt < 2; ++mt) {
      int a = a0 + mt * 16 + l16;
      if (a > LA - 1) a = LA - 1;  // clamp; garbage rows discarded at store
      const float* p = fab + (long)a * H + d0 + kg * 8;
      const f4v w0 = *(const f4v*)p;
      const f4v w1 = *(const f4v*)(p + 4);
      split8(w0, w1, afh[mt], afl[mt]);
    }
#pragma unroll
    for (int nt = 0; nt < 8; ++nt) {
      const long boff = (long)(k0 + nt * 16 + l16) * H + d0 + kg * 8;
      const s8v bh = *(const s8v*)(th + boff);
      const s8v bl = *(const s8v*)(tl + boff);
#pragma unroll
      for (int mt = 0; mt < 2; ++mt) {
        acc[mt][nt] = __builtin_amdgcn_mfma_f32_16x16x32_bf16(afh[mt], bh, acc[mt][nt], 0, 0, 0);
        acc[mt][nt] = __builtin_amdgcn_mfma_f32_16x16x32_bf16(afl[mt], bh, acc[mt][nt], 0, 0, 0);
        acc[mt][nt] = __builtin_amdgcn_mfma_f32_16x16x32_bf16(afh[mt], bl, acc[mt][nt], 0, 0, 0);
      }
    }
  }

  // ---- epilogue step 1: x = acc + bias + fa (in place in acc) ----
  float bval[8], gval[8], beval[8];
#pragma unroll
  for (int nt = 0; nt < 8; ++nt) {
    const int k = k0 + nt * 16 + l16;
    bval[nt] = bias[k];
    gval[nt] = gamma[k];
    beval[nt] = beta[k];
  }
#pragma unroll
  for (int mt = 0; mt < 2; ++mt)
#pragma unroll
    for (int j = 0; j < 4; ++j) {
      int a = a0 + mt * 16 + kg * 4 + j;
      if (a > LA - 1) a = LA - 1;  // clamped loads; rows >= LA never stored
      const float* far = fab + (long)a * H;
#pragma unroll
      for (int nt = 0; nt < 8; ++nt)
        acc[mt][nt][j] += bval[nt] + far[k0 + nt * 16 + l16];
    }

  // ---- step 2: per-row partial sums over this wave's 128-k slice ----
#pragma unroll
  for (int mt = 0; mt < 2; ++mt)
#pragma unroll
    for (int j = 0; j < 4; ++j) {
      float s = 0.f, ss = 0.f;
#pragma unroll
      for (int nt = 0; nt < 8; ++nt) {
        const float v = acc[mt][nt][j];
        s += v;
        ss += v * v;
      }
#pragma unroll
      for (int o = 1; o < 16; o <<= 1) { s += __shfl_xor(s, o); ss += __shfl_xor(ss, o); }
      if (l16 == 0) {
        sums[wv][mt * 16 + kg * 4 + j] = s;
        ssq[wv][mt * 16 + kg * 4 + j] = ss;
      }
    }
  __syncthreads();

  // ---- step 3: final stats per row, normalize, store ----
#pragma unroll
  for (int mt = 0; mt < 2; ++mt)
#pragma unroll
    for (int j = 0; j < 4; ++j) {
      const int rt = mt * 16 + kg * 4 + j;
      float S = 0.f, SS = 0.f;
#pragma unroll
      for (int w = 0; w < 4; ++w) { S += sums[w][rt]; SS += ssq[w][rt]; }
      const float mu = S * (1.f / H);
      const float var = SS * (1.f / H) - mu * mu;
      const float rs = rsqrtf(var + LN_EPS);
      const int a = a0 + rt;
      if (a < LA) {
        float* orow = out + ((long)b * LA + a) * H;
#pragma unroll
        for (int nt = 0; nt < 8; ++nt) {
          const int k = k0 + nt * 16 + l16;
          orow[k] = (acc[mt][nt][j] - mu) * rs * gval[nt] + beval[nt];
        }
      }
    }
}

extern "C" void kernel_launch(void* const* d_in, const int* in_sizes, int n_in,
                              void* d_out, int out_size, void* d_ws, size_t ws_size,
                              hipStream_t stream) {
  const float* fa = (const float*)d_in[0];
  const float* fb = (const float*)d_in[1];
  const float* W = (const float*)d_in[2];
  const float* bias = (const float*)d_in[3];
  const float* gamma = (const float*)d_in[4];
  const float* beta = (const float*)d_in[5];
  float* out = (float*)d_out;
  char* ws = (char*)d_ws;

  float* part = (float*)ws;
  unsigned short* bmh = (unsigned short*)(ws + 524288);
  unsigned short* bml = (unsigned short*)(ws + 557056);
  unsigned short* thi = (unsigned short*)(ws + 589824);
  unsigned short* tlo = (unsigned short*)(ws + 589824 + 16777216);

  hipLaunchKernelGGL(k_bmean_part, dim3(256), dim3(512), 0, stream, fb, part);
  hipLaunchKernelGGL(k_bmean_final, dim3(32), dim3(512), 0, stream, part, bmh, bml);
  hipLaunchKernelGGL(k_wt, dim3((int)(RTOT / 256)), dim3(256), 0, stream, W, bmh, bml, thi, tlo);
  hipLaunchKernelGGL(k_fused_ln, dim3(10, 32), dim3(256), 0, stream, fa, thi, tlo, bias, gamma, beta, out);
}